// Round 3
// baseline (390.513 us; speedup 1.0000x reference)
//
#include <hip/hip_runtime.h>
#include <hip/hip_bf16.h>

// CausalAttention: q=xWq,k=xWk,v=xWv; S=qk^T; causal mask (j>i -> -inf);
// softmax over AXIS=1 (query axis) of S/32; out = W @ v.
// P[i,j]=exp(s_ij/32), l_j=sum_{i>=j} P (fused in P-GEMM epilogue),
// fold 1/l_j into V rows -> out = P @ (V/l)^T.
//
// R8: register-pipelined 8-phase 256^2 GEMM.
// R6/R7 post-mortem: phase time ~1650cy = LDS drain (380-1150cy/CU) + MFMA
// (620cy/SIMD) ADDED serially, because each phase's ds_reads fed its own MFMA
// through lgkmcnt(0) with all 8 waves barrier-locked. Fix: phase p ds_reads
// the frags for phase p+1 and MFMAs frags read at p-1 (compiler emits counted
// lgkmcnt(newer) -> no drain stall); LDS pipe and MFMA pipe now overlap.
// Consume order per K-tile: (ks0,qa0),(ks0,qa1),(ks1,qa0),(ks1,qa1) -> B(ks)
// reused across adjacent phases, A re-read per phase: 24 ds_read_b128/wave/
// K-tile (minimal), frag sets afA/afB/bwA/bwB alternate (static indexing).
// Stage slots: p1=A1B1(t+1), p4=A0B0(t+2), p5=A1B1(t+2), p8=A0B0(t+3).
// WAR + landing guards: lgkmcnt(0)+vmcnt(0) ONLY at p3/p7 (in-flight set
// there is exactly the >=2-phase-old stages -> ~free; buffer overwrite at
// p4/p8 is then safe). Out-of-range K-tiles SOURCE-CLAMPED (uniform counts).
// Geometry: 256x256 tile, BK=64, 8 waves (2Mx4N), per-wave 128x64, 512 thr,
// 128KB LDS, 1 block/CU. LDS XOR swizzle (0 conflicts): phys 16B chunk =
// logical ^ (row&7), global source pre-swizzled, reads XOR with fm&7.
// XCD swizzle + banded traversal kept (R4/R5).

using bf16 = __hip_bfloat16;
typedef __attribute__((ext_vector_type(8))) short short8;
typedef __attribute__((ext_vector_type(4))) float f32x4;
typedef unsigned long long ull;

__device__ __forceinline__ float bfbits2f(unsigned short u) {
  return __uint_as_float((unsigned)u << 16);
}

// ---------------- fp32 -> bf16 convert (x4 per thread) ----------------
__global__ void cvt_kernel(const float* __restrict__ in, bf16* __restrict__ out) {
  size_t i = ((size_t)blockIdx.x * 256 + threadIdx.x) * 4;
  float4 v = *(const float4*)(in + i);
  alignas(8) bf16 h[4] = {__float2bfloat16(v.x), __float2bfloat16(v.y),
                          __float2bfloat16(v.z), __float2bfloat16(v.w)};
  *(unsigned long long*)(out + i) = *(const unsigned long long*)h;
}

// ------- W[k][n] fp32 -> Wt[n][k] bf16 (64x64 LDS transpose, vectorized) -------
// z==3 slice: zero the 8*2048 column-sum buffer (folded launch).
__global__ void wt_kernel(const float* __restrict__ W0, const float* __restrict__ W1,
                          const float* __restrict__ W2, bf16* __restrict__ Wt,
                          float* __restrict__ lbuf) {
  int tid = threadIdx.x;
  if (blockIdx.z == 3) {
    int bid = blockIdx.y * 16 + blockIdx.x;
    if (bid < 64) lbuf[bid * 256 + tid] = 0.f;
    return;
  }
  const float* W = blockIdx.z == 0 ? W0 : blockIdx.z == 1 ? W1 : W2;
  bf16* O = Wt + (size_t)blockIdx.z * 1048576ull;
  __shared__ float t[64][65];
  int n0 = blockIdx.x * 64, k0 = blockIdx.y * 64;
#pragma unroll
  for (int i = 0; i < 4; ++i) {
    int idx = i * 1024 + tid * 4;
    int r = idx >> 6, c = idx & 63;
    float4 v = *(const float4*)(W + (size_t)(k0 + r) * 1024 + n0 + c);
    t[r][c] = v.x; t[r][c + 1] = v.y; t[r][c + 2] = v.z; t[r][c + 3] = v.w;
  }
  __syncthreads();
#pragma unroll
  for (int i = 0; i < 4; ++i) {
    int idx = i * 1024 + tid * 4;
    int r = idx >> 6, c = idx & 63;  // out row n0+r, k cols k0+c..c+3
    alignas(8) bf16 h[4] = {__float2bfloat16(t[c][r]), __float2bfloat16(t[c + 1][r]),
                            __float2bfloat16(t[c + 2][r]), __float2bfloat16(t[c + 3][r])};
    *(unsigned long long*)(O + (size_t)(n0 + r) * 1024 + k0 + c) = *(const unsigned long long*)h;
  }
}

// ------- Vt[e][j] = bf16( V[j][e] / l_j )  (64x64 LDS transpose, vectorized) -------
__global__ void vhat_kernel(const bf16* __restrict__ QKV, const float* __restrict__ l,
                            bf16* __restrict__ Vt) {
  int lb = blockIdx.z;
  const unsigned short* V =
      (const unsigned short*)QKV + ((size_t)lb * 3 + 2) * 2097152ull;  // V slot
  bf16* O = Vt + (size_t)lb * 2097152ull;
  const float* lc = l + lb * 2048;
  __shared__ float t[64][65];
  __shared__ float rl[64];
  int j0 = blockIdx.x * 64, e0 = blockIdx.y * 64;
  int tid = threadIdx.x;
  if (tid < 64) rl[tid] = 1.0f / lc[j0 + tid];
#pragma unroll
  for (int i = 0; i < 4; ++i) {
    int idx = i * 1024 + tid * 4;
    int r = idx >> 6, c = idx & 63;
    ushort4 u = *(const ushort4*)(V + (size_t)(j0 + r) * 1024 + e0 + c);
    t[r][c] = bfbits2f(u.x); t[r][c + 1] = bfbits2f(u.y);
    t[r][c + 2] = bfbits2f(u.z); t[r][c + 3] = bfbits2f(u.w);
  }
  __syncthreads();
#pragma unroll
  for (int i = 0; i < 4; ++i) {
    int idx = i * 1024 + tid * 4;
    int r = idx >> 6, c = idx & 63;  // out row e0+r, cols j0+c..c+3
    alignas(8) bf16 h[4] = {
        __float2bfloat16(t[c][r] * rl[c]), __float2bfloat16(t[c + 1][r] * rl[c + 1]),
        __float2bfloat16(t[c + 2][r] * rl[c + 2]), __float2bfloat16(t[c + 3][r] * rl[c + 3])};
    *(unsigned long long*)(O + (size_t)(e0 + r) * 2048 + j0 + c) = *(const unsigned long long*)h;
  }
}

// ---------------- register-pipelined 256x256 8-phase GEMM ----------------
#define RDA(DST, BUF, QA, KS)                                                   \
  do {                                                                          \
    const bf16* _p = &As[BUF][0][0] + aoff + (QA)*4096;                         \
    const int _c = (((KS)*4 + kg) ^ sw) * 8;                                    \
    _Pragma("unroll") for (int _i = 0; _i < 4; ++_i)                            \
        DST[_i] = *(const short8*)(_p + _i * 1024 + _c);                        \
  } while (0)

#define RDB(DST, BUF, KS)                                                       \
  do {                                                                          \
    const bf16* _p = &Bs[BUF][0][0] + boff;                                     \
    const int _c = (((KS)*4 + kg) ^ sw) * 8;                                    \
    _Pragma("unroll") for (int _j = 0; _j < 4; ++_j)                            \
        DST[_j] = *(const short8*)(_p + _j * 1024 + _c);                        \
  } while (0)

#define MMA16(AF, BW, ACC)                                                      \
  do {                                                                          \
    __builtin_amdgcn_s_setprio(1);                                              \
    _Pragma("unroll") for (int _i = 0; _i < 4; ++_i)                            \
        _Pragma("unroll") for (int _j = 0; _j < 4; ++_j)                        \
            ACC[_i][_j] = __builtin_amdgcn_mfma_f32_16x16x32_bf16(              \
                AF[_i], BW[_j], ACC[_i][_j], 0, 0, 0);                          \
    __builtin_amdgcn_s_setprio(0);                                              \
  } while (0)

#define BAR __builtin_amdgcn_s_barrier()
#define DRAIN                                                                   \
  do {                                                                          \
    asm volatile("s_waitcnt vmcnt(0) lgkmcnt(0)" ::: "memory");                 \
    __builtin_amdgcn_sched_barrier(0);                                          \
  } while (0)

// EPI: 0 = bf16 store (QKV), 1 = P=exp(acc/32) causal-masked + fused column-sum,
//      2 = fp32 store (PV out). VARK: K = (by+1)*256, y reversed (long-K first).
template <int EPI, bool VARK>
__device__ __forceinline__ void gemm256_body(
    const bf16* __restrict__ A, const bf16* __restrict__ B, void* __restrict__ Cv,
    int lda, int ldb, int ldc, int Kin, int zdivA, int zmodB,
    ull sA, ull sB, ull sC, float* __restrict__ lptr) {
  const unsigned gx = gridDim.x, gy = gridDim.y;
  const unsigned per_z = gx * gy;
  const unsigned total = per_z * gridDim.z;
  unsigned id = blockIdx.x + gx * (blockIdx.y + gy * blockIdx.z);
  unsigned lid = (id & 7) * (total >> 3) + (id >> 3);
  const unsigned bz = lid / per_z;
  unsigned rem = lid - bz * per_z;
  constexpr unsigned H = 8;
  const unsigned band = rem / (gx * H);
  const unsigned w = rem - band * (gx * H);
  const unsigned bx = w / H;
  const unsigned by_raw = band * H + (w - bx * H);
  const unsigned by = VARK ? (gy - 1 - by_raw) : by_raw;

  if constexpr (EPI == 1) {
    if (bx > by) return;  // strictly-upper score tile: skip (before any barrier)
  }
  const int z = (int)bz;
  A += (ull)(z / zdivA) * sA;
  B += (ull)(z % zmodB) * sB;
  const int K = VARK ? (int)(by + 1) * 256 : Kin;
  const int NT = K >> 6, NU = NT >> 1;  // K-tiles of 64; iterations of 2 tiles

  alignas(16) __shared__ bf16 As[2][256][64];  // 64KB
  alignas(16) __shared__ bf16 Bs[2][256][64];  // 64KB

  const int tid = threadIdx.x, wave = tid >> 6, lane = tid & 63;
  const int wm = wave >> 2, wn = wave & 3;       // 2M x 4N wave grid
  const int fm = lane & 15, kg = lane >> 4, sw = fm & 7;
  const int m0 = (int)by * 256, n0 = (int)bx * 256;
  const int srow = tid >> 3;                     // staging row 0..63 per 128-row half
  const int scg = ((tid & 7) ^ (srow & 7)) * 8;  // swizzled GLOBAL chunk (elements)
  const int scl = (tid & 7) * 8;                 // linear LDS chunk

  const int aoff = (wm * 128 + fm) * 64;  // + qa*4096 + i*1024 + chunk
  const int boff = (wn * 64 + fm) * 64;   // + j*1024 + chunk

  const bf16* A0r = A + (size_t)m0 * lda;        // rows m0..m0+127
  const bf16* A1r = A0r + (size_t)128 * lda;     // rows m0+128..m0+255
  const bf16* B0r = B + (size_t)n0 * ldb;
  const bf16* B1r = B0r + (size_t)128 * ldb;

  f32x4 acc0[4][4], acc1[4][4];
#pragma unroll
  for (int i = 0; i < 4; ++i)
#pragma unroll
    for (int j = 0; j < 4; ++j) {
      acc0[i][j] = (f32x4){0.f, 0.f, 0.f, 0.f};
      acc1[i][j] = (f32x4){0.f, 0.f, 0.f, 0.f};
    }
  short8 afA[4], afB[4], bwA[4], bwB[4];

  auto stageHalf = [&](const bf16* g, int gld, bf16* l) {
#pragma unroll
    for (int r = 0; r < 2; ++r)
      __builtin_amdgcn_global_load_lds(
          (const __attribute__((address_space(1))) void*)(g + (size_t)(r * 64 + srow) * gld + scg),
          (__attribute__((address_space(3))) void*)(l + (r * 64 + srow) * 64 + scl), 16, 0, 0);
  };

  // prologue: stage tile0 fully + tile1 A0B0; wait tile0 landed (4 allowed out);
  // then read p1's fragments (A(t0,ks0,qa0), B(t0,ks0)).
  stageHalf(A0r, lda, &As[0][0][0]);
  stageHalf(B0r, ldb, &Bs[0][0][0]);
  stageHalf(A1r, lda, &As[0][128][0]);
  stageHalf(B1r, ldb, &Bs[0][128][0]);
  stageHalf(A0r + 64, lda, &As[1][0][0]);
  stageHalf(B0r + 64, ldb, &Bs[1][0][0]);
  asm volatile("s_waitcnt vmcnt(4)" ::: "memory");
  __builtin_amdgcn_sched_barrier(0);
  BAR;
  RDA(afA, 0, 0, 0);
  RDB(bwA, 0, 0);

  for (int u = 0; u < NU; ++u) {
    const int t = 2 * u;
    const int k1 = (t + 1) * 64;
    const int k2 = (t + 2 < NT ? t + 2 : NT - 1) * 64;  // clamp: uniform vmcnt,
    const int k3 = (t + 3 < NT ? t + 3 : NT - 1) * 64;  // slots never consumed
    // p1: MFMA(t,ks0,qa0); RD A(t,ks0,qa1); stage A1B1(t+1)->buf1
    RDA(afB, 0, 1, 0);
    stageHalf(A1r + k1, lda, &As[1][128][0]);
    stageHalf(B1r + k1, ldb, &Bs[1][128][0]);
    BAR; MMA16(afA, bwA, acc0); BAR;
    // p2: MFMA(t,ks0,qa1); RD A(t,ks1,qa0)+B(t,ks1)
    RDA(afA, 0, 0, 1);
    RDB(bwB, 0, 1);
    BAR; MMA16(afB, bwA, acc1); BAR;
    // p3: MFMA(t,ks1,qa0); RD A(t,ks1,qa1); drain (t+1 landed; buf0 reads done)
    RDA(afB, 0, 1, 1);
    BAR; MMA16(afA, bwB, acc0); DRAIN; BAR;
    // p4: MFMA(t,ks1,qa1); RD A(t+1,ks0,qa0)+B(t+1,ks0); stage A0B0(t+2)->buf0
    RDA(afA, 1, 0, 0);
    RDB(bwA, 1, 0);
    stageHalf(A0r + k2, lda, &As[0][0][0]);
    stageHalf(B0r + k2, ldb, &Bs[0][0][0]);
    BAR; MMA16(afB, bwB, acc1); BAR;
    // p5: MFMA(t+1,ks0,qa0); RD A(t+1,ks0,qa1); stage A1B1(t+2)->buf0
    RDA(afB, 1, 1, 0);
    stageHalf(A1r + k2, lda, &As[0][128][0]);
    stageHalf(B1r + k2, ldb, &Bs[0][128][0]);
    BAR; MMA16(afA, bwA, acc0); BAR;
    // p6: MFMA(t+1,ks0,qa1); RD A(t+1,ks1,qa0)+B(t+1,ks1)
    RDA(afA, 1, 0, 1);
    RDB(bwB, 1, 1);
    BAR; MMA16(afB, bwA, acc1); BAR;
    // p7: MFMA(t+1,ks1,qa0); RD A(t+1,ks1,qa1); drain (t+2 landed; buf1 reads done)
    RDA(afB, 1, 1, 1);
    BAR; MMA16(afA, bwB, acc0); DRAIN; BAR;
    // p8: MFMA(t+1,ks1,qa1); RD A(t+2,ks0,qa0)+B(t+2,ks0); stage A0B0(t+3)->buf1
    RDA(afA, 0, 0, 0);
    RDB(bwA, 0, 0);
    stageHalf(A0r + k3, lda, &As[1][0][0]);
    stageHalf(B0r + k3, ldb, &Bs[1][0][0]);
    BAR; MMA16(afB, bwB, acc1); BAR;
  }

  // epilogue — C/D layout: col = lane&15, row = (lane>>4)*4 + reg
  const int cr = kg * 4, cc = fm;
  const int rbase = m0 + wm * 128 + cr;
  const int cbase = n0 + wn * 64 + cc;
  if constexpr (EPI == 2) {
    float* C = (float*)Cv + (ull)z * sC;
#pragma unroll
    for (int i = 0; i < 4; ++i)
#pragma unroll
      for (int j = 0; j < 4; ++j)
#pragma unroll
        for (int r = 0; r < 4; ++r) {
          C[(size_t)(rbase + i * 16 + r) * ldc + (cbase + j * 16)] = acc0[i][j][r];
          C[(size_t)(rbase + 64 + i * 16 + r) * ldc + (cbase + j * 16)] = acc1[i][j][r];
        }
  } else if constexpr (EPI == 0) {
    bf16* C = (bf16*)Cv + (ull)z * sC;
#pragma unroll
    for (int i = 0; i < 4; ++i)
#pragma unroll
      for (int j = 0; j < 4; ++j)
#pragma unroll
        for (int r = 0; r < 4; ++r) {
          C[(size_t)(rbase + i * 16 + r) * ldc + (cbase + j * 16)] =
              __float2bfloat16(acc0[i][j][r]);
          C[(size_t)(rbase + 64 + i * 16 + r) * ldc + (cbase + j * 16)] =
              __float2bfloat16(acc1[i][j][r]);
        }
  } else {
    // EPI == 1: P = exp(acc/32) causal-masked, plus fused column sums into lptr
    bf16* C = (bf16*)Cv + (ull)z * sC;
    float colpart[4] = {0.f, 0.f, 0.f, 0.f};
#pragma unroll
    for (int qa = 0; qa < 2; ++qa)
#pragma unroll
      for (int i = 0; i < 4; ++i)
#pragma unroll
        for (int j = 0; j < 4; ++j)
#pragma unroll
          for (int r = 0; r < 4; ++r) {
            int gm = rbase + qa * 64 + i * 16 + r;
            int gn = cbase + j * 16;
            float v = qa == 0 ? acc0[i][j][r] : acc1[i][j][r];
            float s = v * 0.03125f;                  // 1/sqrt(1024)
            float p = (gn <= gm) ? __expf(s) : 0.f;  // causal: j<=i, else exact 0
            colpart[j] += p;
            C[(size_t)gm * ldc + gn] = __float2bfloat16(p);
          }
    // reduce the 4 row-groups of the wave (lane bits 4,5), then 1 atomic/column
    float* lcol = lptr + (size_t)z * 2048 + n0 + wn * 64;
#pragma unroll
    for (int j = 0; j < 4; ++j) {
      float s = colpart[j];
      s += __shfl_xor(s, 16);
      s += __shfl_xor(s, 32);
      if (lane < 16) atomicAdd(&lcol[j * 16 + lane], s);
    }
  }
}

// Distinct kernel names so rocprof's per-dispatch table separates the three GEMMs.
__global__ __launch_bounds__(512, 2) void gemm_qkv(
    const bf16* __restrict__ A, const bf16* __restrict__ B, void* __restrict__ Cv,
    int lda, int ldb, int ldc, int Kin, int zdivA, int zmodB,
    ull sA, ull sB, ull sC) {
  gemm256_body<0, false>(A, B, Cv, lda, ldb, ldc, Kin, zdivA, zmodB, sA, sB, sC, nullptr);
}
__global__ __launch_bounds__(512, 2) void gemm_scores(
    const bf16* __restrict__ A, const bf16* __restrict__ B, void* __restrict__ Cv,
    int lda, int ldb, int ldc, int Kin, int zdivA, int zmodB,
    ull sA, ull sB, ull sC, float* __restrict__ lptr) {
  gemm256_body<1, false>(A, B, Cv, lda, ldb, ldc, Kin, zdivA, zmodB, sA, sB, sC, lptr);
}
__global__ __launch_bounds__(512, 2) void gemm_pv(
    const bf16* __restrict__ A, const bf16* __restrict__ B, void* __restrict__ Cv,
    int lda, int ldb, int ldc, int Kin, int zdivA, int zmodB,
    ull sA, ull sB, ull sC) {
  gemm256_body<2, true>(A, B, Cv, lda, ldb, ldc, Kin, zdivA, zmodB, sA, sB, sC, nullptr);
}

// ---------------- host ----------------
extern "C" void kernel_launch(void* const* d_in, const int* in_sizes, int n_in,
                              void* d_out, int out_size, void* d_ws, size_t ws_size,
                              hipStream_t stream) {
  const float* x = (const float*)d_in[0];
  const float* Wq = (const float*)d_in[1];
  const float* Wk = (const float*)d_in[2];
  const float* Wv = (const float*)d_in[3];
  float* out = (float*)d_out;

  constexpr unsigned long long X_EL = 2048ull * 1024;  // per batch
  constexpr unsigned long long QKV_EL = 3ull * X_EL;
  constexpr unsigned long long P_EL = 2048ull * 2048;
  constexpr unsigned long long VT_EL = 1024ull * 2048;
  constexpr unsigned long long WT_B = 3ull * 1024 * 1024 * 2;
  constexpr unsigned long long LB_B = 8ull * 2048 * 4;  // column sums, all 8 batches
  constexpr unsigned long long PER_B = 2 * (X_EL + QKV_EL + P_EL + VT_EL);

  size_t NB = 1;
  for (size_t nb : {(size_t)8, (size_t)4, (size_t)2})
    if (WT_B + LB_B + nb * PER_B <= ws_size) { NB = nb; break; }

  char* p = (char*)d_ws;
  bf16* Wt = (bf16*)p;   p += WT_B;
  float* lbuf = (float*)p; p += LB_B;
  bf16* Xb = (bf16*)p;   p += 2 * NB * X_EL;
  bf16* QKV = (bf16*)p;  p += 2 * NB * QKV_EL;
  bf16* P = (bf16*)p;    p += 2 * NB * P_EL;
  bf16* Vt = (bf16*)p;

  // weight transpose + zero lbuf (z==3 slice)
  wt_kernel<<<dim3(16, 16, 4), 256, 0, stream>>>(Wq, Wk, Wv, Wt, lbuf);

  for (size_t b0 = 0; b0 < 8; b0 += NB) {
    // x chunk -> bf16
    cvt_kernel<<<dim3((unsigned)(NB * 2048)), 256, 0, stream>>>(x + b0 * X_EL, Xb);
    // Q,K,V = X @ W  (z = lb*3 + weight)
    gemm_qkv<<<dim3(4, 8, (unsigned)(NB * 3)), 512, 0, stream>>>(
        Xb, Wt, QKV, 1024, 1024, 1024, 1024, 3, 3, X_EL, 1048576ull, X_EL);
    // P = exp(QK^T/32) lower-triangle tiles, causal-masked, fused column sums
    gemm_scores<<<dim3(8, 8, (unsigned)NB), 512, 0, stream>>>(
        QKV, QKV + X_EL, P, 1024, 1024, 2048, 1024, 1, 1 << 30, QKV_EL, QKV_EL, P_EL,
        lbuf + b0 * 2048);
    vhat_kernel<<<dim3(32, 16, (unsigned)NB), 256, 0, stream>>>(QKV, lbuf + b0 * 2048, Vt);
    // out = P @ Vt^T, K stops at diagonal tile
    gemm_pv<<<dim3(4, 8, (unsigned)NB), 512, 0, stream>>>(
        P, Vt, out + b0 * X_EL, 2048, 2048, 1024, 0, 1, 1 << 30, P_EL, VT_EL, X_EL);
  }
}

// Round 4
// 335.591 us; speedup vs baseline: 1.1637x; 1.1637x over previous
//
#include <hip/hip_runtime.h>
#include <hip/hip_bf16.h>

// CausalAttention: q=xWq,k=xWk,v=xWv; S=qk^T; causal mask (j>i -> -inf);
// softmax over AXIS=1 (query axis, i.e. COLUMN-wise over i) of S/32; out = W @ v.
// Strategy: P[i,j]=exp(s_ij/32) (no max-sub needed: |s/32|<~2.5), l_j=sum_{i>=j} P
// (fused into P-GEMM epilogue), fold 1/l_j into V rows -> out = P @ (V/l)^T.
// bf16 MFMA GEMMs, XOR-swizzled LDS (0 bank conflicts), XCD-aware block swizzle
// (R4: QKV FETCH hit the 80MB analytic floor) + banded traversal within XCD
// (R5: B-tile read once per band, A-band L2-resident -> kills P/PV L2 thrash).
// R6-R8 (8-phase 256^2 ports) all regressed (120-132us vs 103us, MfmaUtil ~33%):
// phase cost ~1500cy insensitive to ds_read volume AND vmcnt schedule -> reverted
// to this proven 128^2 2-barrier structure. R9: launch-level only changes:
//  - gemm_qkv split into 2x1536-block launches (surfaces scores/pv in rocprof
//    top-5; 1536 = 2 exact occupancy fills, decode math unchanged)
//  - wt + lbuf-zero + first-chunk cvt fused into one pre_kernel launch.
// NOTE: __launch_bounds__ MUST be (256,4): acc needs 64 AGPR + 64 VGPR = 128/wave
// (unified file, ~512/SIMD-slot). (256,5) spills accumulators: 448MB WRITE, 3x slower (R3).

using bf16 = __hip_bfloat16;
typedef __attribute__((ext_vector_type(8))) short short8;
typedef __attribute__((ext_vector_type(4))) float f32x4;

__device__ __forceinline__ float bfbits2f(unsigned short u) {
  return __uint_as_float((unsigned)u << 16);
}

// ---------------- fp32 -> bf16 convert (x4 per thread) ----------------
__global__ void cvt_kernel(const float* __restrict__ in, bf16* __restrict__ out) {
  size_t i = ((size_t)blockIdx.x * 256 + threadIdx.x) * 4;
  float4 v = *(const float4*)(in + i);
  alignas(8) bf16 h[4] = {__float2bfloat16(v.x), __float2bfloat16(v.y),
                          __float2bfloat16(v.z), __float2bfloat16(v.w)};
  *(unsigned long long*)(out + i) = *(const unsigned long long*)h;
}

// ------- fused pre-pass: W transpose (z 0..2) + lbuf zero (z==3) + cvt (z>=4) -------
// wt: W[k][n] fp32 -> Wt[n][k] bf16 (64x64 LDS transpose, vectorized).
// cvt: first-chunk x fp32 -> bf16, block cb = (z-4)*256 + by*16 + bx.
__global__ void pre_kernel(const float* __restrict__ x,
                           const float* __restrict__ W0, const float* __restrict__ W1,
                           const float* __restrict__ W2, bf16* __restrict__ Wt,
                           float* __restrict__ lbuf, bf16* __restrict__ Xb) {
  int tid = threadIdx.x;
  int zz = blockIdx.z;
  if (zz == 3) {
    int bid = blockIdx.y * 16 + blockIdx.x;
    if (bid < 64) lbuf[bid * 256 + tid] = 0.f;
    return;
  }
  if (zz >= 4) {
    size_t cb = (size_t)(zz - 4) * 256 + blockIdx.y * 16 + blockIdx.x;
    size_t i = (cb * 256 + tid) * 4;
    float4 v = *(const float4*)(x + i);
    alignas(8) bf16 h[4] = {__float2bfloat16(v.x), __float2bfloat16(v.y),
                            __float2bfloat16(v.z), __float2bfloat16(v.w)};
    *(unsigned long long*)(Xb + i) = *(const unsigned long long*)h;
    return;
  }
  const float* W = zz == 0 ? W0 : zz == 1 ? W1 : W2;
  bf16* O = Wt + (size_t)zz * 1048576ull;
  __shared__ float t[64][65];
  int n0 = blockIdx.x * 64, k0 = blockIdx.y * 64;
#pragma unroll
  for (int i = 0; i < 4; ++i) {
    int idx = i * 1024 + tid * 4;
    int r = idx >> 6, c = idx & 63;
    float4 v = *(const float4*)(W + (size_t)(k0 + r) * 1024 + n0 + c);
    t[r][c] = v.x; t[r][c + 1] = v.y; t[r][c + 2] = v.z; t[r][c + 3] = v.w;
  }
  __syncthreads();
#pragma unroll
  for (int i = 0; i < 4; ++i) {
    int idx = i * 1024 + tid * 4;
    int r = idx >> 6, c = idx & 63;  // out row n0+r, k cols k0+c..c+3
    alignas(8) bf16 h[4] = {__float2bfloat16(t[c][r]), __float2bfloat16(t[c + 1][r]),
                            __float2bfloat16(t[c + 2][r]), __float2bfloat16(t[c + 3][r])};
    *(unsigned long long*)(O + (size_t)(n0 + r) * 1024 + k0 + c) = *(const unsigned long long*)h;
  }
}

// ------- Vt[e][j] = bf16( V[j][e] / l_j )  (64x64 LDS transpose, vectorized) -------
__global__ void vhat_kernel(const bf16* __restrict__ QKV, const float* __restrict__ l,
                            bf16* __restrict__ Vt) {
  int lb = blockIdx.z;
  const unsigned short* V =
      (const unsigned short*)QKV + ((size_t)lb * 3 + 2) * 2097152ull;  // V slot
  bf16* O = Vt + (size_t)lb * 2097152ull;
  const float* lc = l + lb * 2048;
  __shared__ float t[64][65];
  __shared__ float rl[64];
  int j0 = blockIdx.x * 64, e0 = blockIdx.y * 64;
  int tid = threadIdx.x;
  if (tid < 64) rl[tid] = 1.0f / lc[j0 + tid];
#pragma unroll
  for (int i = 0; i < 4; ++i) {
    int idx = i * 1024 + tid * 4;
    int r = idx >> 6, c = idx & 63;
    ushort4 u = *(const ushort4*)(V + (size_t)(j0 + r) * 1024 + e0 + c);
    t[r][c] = bfbits2f(u.x); t[r][c + 1] = bfbits2f(u.y);
    t[r][c + 2] = bfbits2f(u.z); t[r][c + 3] = bfbits2f(u.w);
  }
  __syncthreads();
#pragma unroll
  for (int i = 0; i < 4; ++i) {
    int idx = i * 1024 + tid * 4;
    int r = idx >> 6, c = idx & 63;  // out row e0+r, cols j0+c..c+3
    alignas(8) bf16 h[4] = {
        __float2bfloat16(t[c][r] * rl[c]), __float2bfloat16(t[c + 1][r] * rl[c + 1]),
        __float2bfloat16(t[c + 2][r] * rl[c + 2]), __float2bfloat16(t[c + 3][r] * rl[c + 3])};
    *(unsigned long long*)(O + (size_t)(e0 + r) * 2048 + j0 + c) = *(const unsigned long long*)h;
  }
}

// ---------------- bt-GEMM body: C[m,n] = sum_k A[m,k]*B[n,k], 128x128 tile, BK=64 ----------------
// LDS XOR-swizzle: physical 16B-chunk = logical ^ (row&7); staging permutes the GLOBAL source
// chunk (keeps global_load_lds wave-uniform dest); fragment reads XOR with fm&7 -> 0 conflicts.
// Block decode: XCD swizzle (lid=(id%8)*(total/8)+id/8 -> contiguous logical range per XCD)
// then BANDED traversal: bands of H=8 rows, x outer / h inner -> consecutive blocks share one
// B tile (read once per band) while the A band (<=3.2MB) stays resident in the XCD's 4MB L2.
// EPI: 0 = bf16 store (QKV), 1 = P=exp(acc/32) causal-masked + fused column-sum -> lptr,
//      2 = fp32 store (PV out). VARK: K = (by+1)*128, y reversed (long-K blocks first).
template <int EPI, bool VARK>
__device__ __forceinline__ void gemm_bt_body(
    const bf16* __restrict__ A, const bf16* __restrict__ B, void* __restrict__ Cv,
    int lda, int ldb, int ldc, int Kin, int zdivA, int zmodB,
    unsigned long long sA, unsigned long long sB, unsigned long long sC,
    float* __restrict__ lptr) {
  const unsigned gx = gridDim.x, gy = gridDim.y;
  const unsigned per_z = gx * gy;
  const unsigned total = per_z * gridDim.z;
  unsigned id = blockIdx.x + gx * (blockIdx.y + gy * blockIdx.z);
  unsigned lid = (id & 7) * (total >> 3) + (id >> 3);
  const unsigned bz = lid / per_z;
  unsigned rem = lid - bz * per_z;
  constexpr unsigned H = 8;  // band height (gy=16 -> 2 bands per z)
  const unsigned band = rem / (gx * H);
  const unsigned w = rem - band * (gx * H);
  const unsigned bx = w / H;
  const unsigned by_raw = band * H + (w - bx * H);
  const unsigned by = VARK ? (gy - 1 - by_raw) : by_raw;

  if constexpr (EPI == 1) {
    if (bx > by) return;  // strictly-upper score tile: skip
  }
  const int z = (int)bz;
  A += (unsigned long long)(z / zdivA) * sA;
  B += (unsigned long long)(z % zmodB) * sB;
  const int K = VARK ? (int)(by + 1) * 128 : Kin;

  alignas(16) __shared__ bf16 As[128 * 64];
  alignas(16) __shared__ bf16 Bs[128 * 64];

  const int tid = threadIdx.x, wave = tid >> 6, lane = tid & 63;
  const int m0 = by * 128, n0 = bx * 128;
  const int srow = tid >> 3;                        // staging row (per 32-row group)
  const int scol_g = ((tid & 7) ^ (srow & 7)) * 8;  // swizzled GLOBAL chunk
  const int scol_l = (tid & 7) * 8;                 // physical LDS chunk
  const int wm = (wave >> 1) * 64, wn = (wave & 1) * 64;
  const int fm = lane & 15, sw = lane & 7, kg = lane >> 4;

  f32x4 acc[4][4];
#pragma unroll
  for (int mi = 0; mi < 4; ++mi)
#pragma unroll
    for (int ni = 0; ni < 4; ++ni) acc[mi][ni] = (f32x4){0.f, 0.f, 0.f, 0.f};

  const bf16* Arow = A + (size_t)m0 * lda;
  const bf16* Brow = B + (size_t)n0 * ldb;

  for (int k0 = 0; k0 < K; k0 += 64) {
    __syncthreads();  // previous iteration's LDS reads done
#pragma unroll
    for (int c = 0; c < 4; ++c) {
      int row = c * 32 + srow;
      __builtin_amdgcn_global_load_lds(
          (const __attribute__((address_space(1))) void*)(Arow + (size_t)row * lda + k0 + scol_g),
          (__attribute__((address_space(3))) void*)(As + row * 64 + scol_l), 16, 0, 0);
    }
#pragma unroll
    for (int c = 0; c < 4; ++c) {
      int row = c * 32 + srow;
      __builtin_amdgcn_global_load_lds(
          (const __attribute__((address_space(1))) void*)(Brow + (size_t)row * ldb + k0 + scol_g),
          (__attribute__((address_space(3))) void*)(Bs + row * 64 + scol_l), 16, 0, 0);
    }
    __syncthreads();  // drains vmcnt -> staging visible
#pragma unroll
    for (int ks = 0; ks < 2; ++ks) {
      const int pc = ((ks * 4 + kg) ^ sw) * 8;  // swizzled chunk for this lane's rows
      short8 af[4], bf_[4];
#pragma unroll
      for (int i = 0; i < 4; ++i) {
        af[i] = *(const short8*)(As + (wm + i * 16 + fm) * 64 + pc);
        bf_[i] = *(const short8*)(Bs + (wn + i * 16 + fm) * 64 + pc);
      }
#pragma unroll
      for (int mi = 0; mi < 4; ++mi)
#pragma unroll
        for (int ni = 0; ni < 4; ++ni)
          acc[mi][ni] = __builtin_amdgcn_mfma_f32_16x16x32_bf16(af[mi], bf_[ni], acc[mi][ni], 0, 0, 0);
    }
  }

  // epilogue — C/D layout: col = lane&15, row = (lane>>4)*4 + reg
  const int cr = kg * 4, cc = fm;
  if constexpr (EPI == 2) {
    float* C = (float*)Cv + (unsigned long long)z * sC;
#pragma unroll
    for (int mi = 0; mi < 4; ++mi)
#pragma unroll
      for (int ni = 0; ni < 4; ++ni)
#pragma unroll
        for (int r = 0; r < 4; ++r)
          C[(size_t)(m0 + wm + mi * 16 + cr + r) * ldc + (n0 + wn + ni * 16 + cc)] = acc[mi][ni][r];
  } else if constexpr (EPI == 0) {
    bf16* C = (bf16*)Cv + (unsigned long long)z * sC;
#pragma unroll
    for (int mi = 0; mi < 4; ++mi)
#pragma unroll
      for (int ni = 0; ni < 4; ++ni)
#pragma unroll
        for (int r = 0; r < 4; ++r)
          C[(size_t)(m0 + wm + mi * 16 + cr + r) * ldc + (n0 + wn + ni * 16 + cc)] =
              __float2bfloat16(acc[mi][ni][r]);
  } else {
    // EPI == 1: P = exp(acc/32) causal-masked, plus fused column sums into lptr
    bf16* C = (bf16*)Cv + (unsigned long long)z * sC;
    float colpart[4] = {0.f, 0.f, 0.f, 0.f};
#pragma unroll
    for (int mi = 0; mi < 4; ++mi)
#pragma unroll
      for (int ni = 0; ni < 4; ++ni)
#pragma unroll
        for (int r = 0; r < 4; ++r) {
          int gm = m0 + wm + mi * 16 + cr + r;
          int gn = n0 + wn + ni * 16 + cc;
          float s = acc[mi][ni][r] * 0.03125f;     // 1/sqrt(1024)
          float p = (gn <= gm) ? __expf(s) : 0.f;  // causal: j<=i, else exact 0
          colpart[ni] += p;
          C[(size_t)gm * ldc + gn] = __float2bfloat16(p);
        }
    // reduce the 4 row-groups of the wave (lane bits 4,5), then 1 atomic/column
    float* lcol = lptr + (size_t)z * 2048 + n0 + wn;
#pragma unroll
    for (int ni = 0; ni < 4; ++ni) {
      float s = colpart[ni];
      s += __shfl_xor(s, 16);
      s += __shfl_xor(s, 32);
      if (lane < 16) atomicAdd(&lcol[ni * 16 + lane], s);
    }
  }
}

// Distinct kernel names so rocprof's per-dispatch table separates the three GEMMs.
__global__ __launch_bounds__(256, 4) void gemm_qkv(
    const bf16* __restrict__ A, const bf16* __restrict__ B, void* __restrict__ Cv,
    int lda, int ldb, int ldc, int Kin, int zdivA, int zmodB,
    unsigned long long sA, unsigned long long sB, unsigned long long sC) {
  gemm_bt_body<0, false>(A, B, Cv, lda, ldb, ldc, Kin, zdivA, zmodB, sA, sB, sC, nullptr);
}
__global__ __launch_bounds__(256, 4) void gemm_scores(
    const bf16* __restrict__ A, const bf16* __restrict__ B, void* __restrict__ Cv,
    int lda, int ldb, int ldc, int Kin, int zdivA, int zmodB,
    unsigned long long sA, unsigned long long sB, unsigned long long sC,
    float* __restrict__ lptr) {
  gemm_bt_body<1, false>(A, B, Cv, lda, ldb, ldc, Kin, zdivA, zmodB, sA, sB, sC, lptr);
}
__global__ __launch_bounds__(256, 4) void gemm_pv(
    const bf16* __restrict__ A, const bf16* __restrict__ B, void* __restrict__ Cv,
    int lda, int ldb, int ldc, int Kin, int zdivA, int zmodB,
    unsigned long long sA, unsigned long long sB, unsigned long long sC) {
  gemm_bt_body<2, true>(A, B, Cv, lda, ldb, ldc, Kin, zdivA, zmodB, sA, sB, sC, nullptr);
}

// ---------------- host ----------------
extern "C" void kernel_launch(void* const* d_in, const int* in_sizes, int n_in,
                              void* d_out, int out_size, void* d_ws, size_t ws_size,
                              hipStream_t stream) {
  const float* x = (const float*)d_in[0];
  const float* Wq = (const float*)d_in[1];
  const float* Wk = (const float*)d_in[2];
  const float* Wv = (const float*)d_in[3];
  float* out = (float*)d_out;

  constexpr unsigned long long X_EL = 2048ull * 1024;  // per batch
  constexpr unsigned long long QKV_EL = 3ull * X_EL;
  constexpr unsigned long long P_EL = 2048ull * 2048;
  constexpr unsigned long long VT_EL = 1024ull * 2048;
  constexpr unsigned long long WT_B = 3ull * 1024 * 1024 * 2;
  constexpr unsigned long long LB_B = 8ull * 2048 * 4;  // column sums, all 8 batches
  constexpr unsigned long long PER_B = 2 * (X_EL + QKV_EL + P_EL + VT_EL);

  size_t NB = 1;
  for (size_t nb : {(size_t)8, (size_t)4, (size_t)2})
    if (WT_B + LB_B + nb * PER_B <= ws_size) { NB = nb; break; }

  char* p = (char*)d_ws;
  bf16* Wt = (bf16*)p;   p += WT_B;
  float* lbuf = (float*)p; p += LB_B;
  bf16* Xb = (bf16*)p;   p += 2 * NB * X_EL;
  bf16* QKV = (bf16*)p;  p += 2 * NB * QKV_EL;
  bf16* P = (bf16*)p;    p += 2 * NB * P_EL;
  bf16* Vt = (bf16*)p;

  // fused: weight transpose (z 0-2) + zero lbuf (z 3) + first-chunk cvt (z>=4)
  pre_kernel<<<dim3(16, 16, (unsigned)(4 + NB * 8)), 256, 0, stream>>>(
      x, Wq, Wk, Wv, Wt, lbuf, Xb);

  for (size_t b0 = 0; b0 < 8; b0 += NB) {
    // x chunk -> bf16 (first chunk already converted by pre_kernel)
    if (b0)
      cvt_kernel<<<dim3((unsigned)(NB * 2048)), 256, 0, stream>>>(x + b0 * X_EL, Xb);
    // Q,K,V = X @ W  (z = lb*3 + weight); split into two launches so rocprof's
    // top-5 can surface scores/pv (each half = 1536 blocks = 2 occupancy fills)
    const size_t nbA = NB / 2, nbB = NB - nbA;
    if (nbA)
      gemm_qkv<<<dim3(8, 16, (unsigned)(nbA * 3)), 256, 0, stream>>>(
          Xb, Wt, QKV, 1024, 1024, 1024, 1024, 3, 3, X_EL, 1048576ull, X_EL);
    gemm_qkv<<<dim3(8, 16, (unsigned)(nbB * 3)), 256, 0, stream>>>(
        Xb + nbA * X_EL, Wt, QKV + nbA * QKV_EL, 1024, 1024, 1024, 1024, 3, 3,
        X_EL, 1048576ull, X_EL);
    // P = exp(QK^T/32) lower-triangle tiles, causal-masked, fused column sums
    gemm_scores<<<dim3(16, 16, (unsigned)NB), 256, 0, stream>>>(
        QKV, QKV + X_EL, P, 1024, 1024, 2048, 1024, 1, 1 << 30, QKV_EL, QKV_EL, P_EL,
        lbuf + b0 * 2048);
    vhat_kernel<<<dim3(32, 16, (unsigned)NB), 256, 0, stream>>>(QKV, lbuf + b0 * 2048, Vt);
    // out = P @ Vt^T, K stops at diagonal tile
    gemm_pv<<<dim3(8, 16, (unsigned)NB), 256, 0, stream>>>(
        P, Vt, out + b0 * X_EL, 2048, 2048, 1024, 0, 1, 1 << 30, P_EL, VT_EL, X_EL);
  }
}